// Round 4
// baseline (2378.324 us; speedup 1.0000x reference)
//
#include <hip/hip_runtime.h>
#include <math.h>

#define IN_DIM 1024
#define M_DIM  256
#define R_TOT  32768          // B*S = 8*4096
#define TM     32             // rows per block
#define KB     16             // k-chunk for phase 1
#define EPS    1e-12f

// ---------------------------------------------------------------------------
// Fused POVM kernel. No d_ws use (256 KB scratch write aborted in round 1).
// Output layout is resolved AT RUNTIME from out_size in kernel_launch:
//   out_size == 75,497,472: PLANAR [re: R*IN][im: R*IN][probs: R*M]  (fp32)
//   out_size == 41,943,040: [re: R*IN][probs: R*M]  (complex ref cast to
//                           float32 -> real part only; im region width 0)
//   else:                   derived planar split.
// EVERY global store is region-guarded so no hypothesis can fault.
// Phases per 32-row tile:
//   1: inner[r][m] = sum_i psi[r][i]*conj(basis[m][i])   (reg-tiled GEMM)
//   2: p=|inner|^2, probs = p/(sum+eps), store probs (global + LDS)
//   3: collapsed_unscaled = probs @ basis, accumulate per-row normsq in regs,
//      store unscaled
//   4: re-read own stores, multiply by 1/(sqrt(normsq)+eps)
// ---------------------------------------------------------------------------
__global__ __launch_bounds__(256) void povm_kernel(
    const float* __restrict__ psi_re, const float* __restrict__ psi_im,
    const float* __restrict__ basis_re, const float* __restrict__ basis_im,
    float* __restrict__ out,
    long long off_im,       // float offset of imag plane (== off_probs if none)
    long long off_probs,    // float offset of probs chunk
    long long cap)          // total float capacity (= out_size)
{
    __shared__ __align__(16) float sPsi[KB][TM][2];      // 4 KB
    __shared__ __align__(16) float sBig[KB * M_DIM * 2]; // 32 KB; basis tile, then probs[TM][M]
    __shared__ __align__(16) float sScale[TM];

    const int tid  = threadIdx.x;
    const int tr   = tid >> 5;          // 0..7  -> rows 4*tr..4*tr+3
    const int tm   = tid & 31;          // 0..31 -> cols 8*tm..8*tm+7
    const int row0 = blockIdx.x * TM;

    float accRe[4][8];
    float accIm[4][8];
    #pragma unroll
    for (int a = 0; a < 4; ++a)
        #pragma unroll
        for (int b = 0; b < 8; ++b) { accRe[a][b] = 0.f; accIm[a][b] = 0.f; }

    // -------- phase 1: inner GEMM --------
    const int p_arr = tid >> 7;             // 0=re, 1=im
    const int p_row = (tid >> 2) & 31;
    const int p_kq  = tid & 3;
    const float* p_src  = p_arr ? psi_im : psi_re;
    const float* p_base = p_src + (size_t)(row0 + p_row) * IN_DIM + p_kq * 4;
    const int b_kq = tid & 3;
    const int b_m0 = tid >> 2;              // 0..63

    for (int kc = 0; kc < IN_DIM; kc += KB) {
        float4 pv = *(const float4*)(p_base + kc);
        sPsi[p_kq * 4 + 0][p_row][p_arr] = pv.x;
        sPsi[p_kq * 4 + 1][p_row][p_arr] = pv.y;
        sPsi[p_kq * 4 + 2][p_row][p_arr] = pv.z;
        sPsi[p_kq * 4 + 3][p_row][p_arr] = pv.w;
        #pragma unroll
        for (int j = 0; j < 4; ++j) {
            const int m = b_m0 + 64 * j;
            const float4 vr = *(const float4*)(basis_re + (size_t)m * IN_DIM + kc + b_kq * 4);
            const float4 vi = *(const float4*)(basis_im + (size_t)m * IN_DIM + kc + b_kq * 4);
            const int kb0 = b_kq * 4;
            *(float2*)&sBig[((kb0 + 0) * M_DIM + m) * 2] = make_float2(vr.x, vi.x);
            *(float2*)&sBig[((kb0 + 1) * M_DIM + m) * 2] = make_float2(vr.y, vi.y);
            *(float2*)&sBig[((kb0 + 2) * M_DIM + m) * 2] = make_float2(vr.z, vi.z);
            *(float2*)&sBig[((kb0 + 3) * M_DIM + m) * 2] = make_float2(vr.w, vi.w);
        }
        __syncthreads();
        #pragma unroll
        for (int kk = 0; kk < KB; ++kk) {
            const float4 pa = *(const float4*)&sPsi[kk][4 * tr][0];
            const float4 pb = *(const float4*)&sPsi[kk][4 * tr + 2][0];
            const float4 b0 = *(const float4*)&sBig[(kk * M_DIM + 8 * tm) * 2 + 0];
            const float4 b1 = *(const float4*)&sBig[(kk * M_DIM + 8 * tm) * 2 + 4];
            const float4 b2 = *(const float4*)&sBig[(kk * M_DIM + 8 * tm) * 2 + 8];
            const float4 b3 = *(const float4*)&sBig[(kk * M_DIM + 8 * tm) * 2 + 12];
            const float pr[4] = {pa.x, pa.z, pb.x, pb.z};
            const float pi[4] = {pa.y, pa.w, pb.y, pb.w};
            const float rv[8] = {b0.x, b0.z, b1.x, b1.z, b2.x, b2.z, b3.x, b3.z};
            const float iv[8] = {b0.y, b0.w, b1.y, b1.w, b2.y, b2.w, b3.y, b3.w};
            #pragma unroll
            for (int a = 0; a < 4; ++a)
                #pragma unroll
                for (int b = 0; b < 8; ++b) {
                    accRe[a][b] = fmaf(pr[a], rv[b], fmaf(pi[a], iv[b], accRe[a][b]));
                    accIm[a][b] = fmaf(pi[a], rv[b], fmaf(-pr[a], iv[b], accIm[a][b]));
                }
        }
        __syncthreads();
    }

    // -------- phase 2: p = |inner|^2, probs --------
    float rowsum[4] = {0.f, 0.f, 0.f, 0.f};
    #pragma unroll
    for (int a = 0; a < 4; ++a)
        #pragma unroll
        for (int b = 0; b < 8; ++b) {
            const float p = accRe[a][b] * accRe[a][b] + accIm[a][b] * accIm[a][b];
            accRe[a][b] = p;
            rowsum[a] += p;
        }
    #pragma unroll
    for (int off = 1; off < 32; off <<= 1) {
        #pragma unroll
        for (int a = 0; a < 4; ++a)
            rowsum[a] += __shfl_xor(rowsum[a], off, 64);
    }
    float* sProbs = sBig;               // aliased: [TM][M_DIM]
    #pragma unroll
    for (int a = 0; a < 4; ++a) {
        const float inv = 1.f / (rowsum[a] + EPS);
        #pragma unroll
        for (int b = 0; b < 8; ++b) accRe[a][b] *= inv;   // accRe = probs
        const int row = 4 * tr + a;
        const float4 q0 = make_float4(accRe[a][0], accRe[a][1], accRe[a][2], accRe[a][3]);
        const float4 q1 = make_float4(accRe[a][4], accRe[a][5], accRe[a][6], accRe[a][7]);
        *(float4*)&sProbs[row * M_DIM + 8 * tm + 0] = q0;
        *(float4*)&sProbs[row * M_DIM + 8 * tm + 4] = q1;
        const long long po = off_probs + (long long)(row0 + row) * M_DIM + 8 * tm;
        if (po + 8 <= cap) {
            *(float4*)(out + po)     = q0;
            *(float4*)(out + po + 4) = q1;
        }
    }
    __syncthreads();

    // -------- phase 3: collapsed_unscaled = probs @ basis, accumulate normsq --------
    float nsq[4] = {0.f, 0.f, 0.f, 0.f};
    for (int ic = 0; ic < 4; ++ic) {
        #pragma unroll
        for (int a = 0; a < 4; ++a)
            #pragma unroll
            for (int b = 0; b < 8; ++b) { accRe[a][b] = 0.f; accIm[a][b] = 0.f; }
        const int i0 = ic * 256 + 8 * tm;
        for (int m = 0; m < M_DIM; ++m) {
            const float* brp = basis_re + (size_t)m * IN_DIM + i0;
            const float* bip = basis_im + (size_t)m * IN_DIM + i0;
            const float4 br0 = *(const float4*)(brp);
            const float4 br1 = *(const float4*)(brp + 4);
            const float4 bi0 = *(const float4*)(bip);
            const float4 bi1 = *(const float4*)(bip + 4);
            const float rv[8] = {br0.x, br0.y, br0.z, br0.w, br1.x, br1.y, br1.z, br1.w};
            const float iv[8] = {bi0.x, bi0.y, bi0.z, bi0.w, bi1.x, bi1.y, bi1.z, bi1.w};
            float pvv[4];
            #pragma unroll
            for (int a = 0; a < 4; ++a) pvv[a] = sProbs[(4 * tr + a) * M_DIM + m];
            #pragma unroll
            for (int a = 0; a < 4; ++a)
                #pragma unroll
                for (int b = 0; b < 8; ++b) {
                    accRe[a][b] = fmaf(pvv[a], rv[b], accRe[a][b]);
                    accIm[a][b] = fmaf(pvv[a], iv[b], accIm[a][b]);
                }
        }
        #pragma unroll
        for (int a = 0; a < 4; ++a) {
            const int row = 4 * tr + a;
            #pragma unroll
            for (int b = 0; b < 8; ++b)
                nsq[a] += accRe[a][b] * accRe[a][b] + accIm[a][b] * accIm[a][b];
            const long long o = (long long)(row0 + row) * IN_DIM + i0;
            if (o + 8 <= off_im) {                 // real plane region
                *(float4*)(out + o)     = make_float4(accRe[a][0], accRe[a][1], accRe[a][2], accRe[a][3]);
                *(float4*)(out + o + 4) = make_float4(accRe[a][4], accRe[a][5], accRe[a][6], accRe[a][7]);
            }
            const long long oi = off_im + o;
            if (oi + 8 <= off_probs) {             // imag plane region (may be width 0)
                *(float4*)(out + oi)     = make_float4(accIm[a][0], accIm[a][1], accIm[a][2], accIm[a][3]);
                *(float4*)(out + oi + 4) = make_float4(accIm[a][4], accIm[a][5], accIm[a][6], accIm[a][7]);
            }
        }
    }

    // reduce normsq across the 32 tm lanes (within wave half)
    #pragma unroll
    for (int off = 1; off < 32; off <<= 1) {
        #pragma unroll
        for (int a = 0; a < 4; ++a)
            nsq[a] += __shfl_xor(nsq[a], off, 64);
    }
    if (tm == 0) {
        #pragma unroll
        for (int a = 0; a < 4; ++a)
            sScale[4 * tr + a] = 1.f / (sqrtf(nsq[a]) + EPS);
    }
    __syncthreads();

    // -------- phase 4: rescale own writes --------
    for (int ic = 0; ic < 4; ++ic) {
        const int i0 = ic * 256 + 8 * tm;
        #pragma unroll
        for (int a = 0; a < 4; ++a) {
            const int row = 4 * tr + a;
            const float s = sScale[row];
            const long long o = (long long)(row0 + row) * IN_DIM + i0;
            if (o + 8 <= off_im) {
                #pragma unroll
                for (int q = 0; q < 2; ++q) {
                    float4 v = *(float4*)(out + o + 4 * q);
                    v.x *= s; v.y *= s; v.z *= s; v.w *= s;
                    *(float4*)(out + o + 4 * q) = v;
                }
            }
            const long long oi = off_im + o;
            if (oi + 8 <= off_probs) {
                #pragma unroll
                for (int q = 0; q < 2; ++q) {
                    float4 w = *(float4*)(out + oi + 4 * q);
                    w.x *= s; w.y *= s; w.z *= s; w.w *= s;
                    *(float4*)(out + oi + 4 * q) = w;
                }
            }
        }
    }
}

extern "C" void kernel_launch(void* const* d_in, const int* in_sizes, int n_in,
                              void* d_out, int out_size, void* d_ws, size_t ws_size,
                              hipStream_t stream)
{
    const float* psi_re   = (const float*)d_in[0];
    const float* psi_im   = (const float*)d_in[1];
    const float* basis_re = (const float*)d_in[2];
    const float* basis_im = (const float*)d_in[3];

    const long long RIN = (long long)R_TOT * IN_DIM;   // 33,554,432
    const long long RM  = (long long)R_TOT * M_DIM;    //  8,388,608
    const long long cap = (long long)out_size;

    long long off_im, off_probs;
    if (cap == 2 * RIN + RM) {            // planar re/im + probs (75,497,472)
        off_im = RIN; off_probs = 2 * RIN;
    } else if (cap == RIN + RM) {         // real-part-only + probs (41,943,040)
        off_im = RIN; off_probs = RIN;    // imag region width 0 -> guards skip
    } else {                              // fallback: derived planar split
        long long plane = (cap - RM) / 2;
        if (plane < 0) plane = 0;
        off_im = plane; off_probs = 2 * plane;
    }

    povm_kernel<<<R_TOT / TM, 256, 0, stream>>>(psi_re, psi_im, basis_re, basis_im,
                                                (float*)d_out, off_im, off_probs, cap);
}